// Round 1
// baseline (175.156 us; speedup 1.0000x reference)
//
#include <hip/hip_runtime.h>
#include <math.h>

#define N_SMPS 16384
#define N_FCNS 2048
#define D_IN 32
#define D_OUT 32
#define KNN 4

// ---------------- Kernel 1: distance + top-k (with fp64 refinement) ----------
#define K1_BLOCK 512
#define K1_SAMPLES 64                  // samples per block (= lanes per wave)
#define K1_SPLITS 8                    // waves per block, each covers a center split
#define K1_CPS (N_FCNS / K1_SPLITS)    // 256 centers per split

__global__ __launch_bounds__(K1_BLOCK) void k_topk(
    const float* __restrict__ x, const float* __restrict__ ctrs,
    int* __restrict__ idx_out)
{
  __shared__ float s_hcsq[N_FCNS];
  __shared__ float s_u[K1_SPLITS][K1_SAMPLES][4];
  __shared__ int   s_i[K1_SPLITS][K1_SAMPLES][4];

  const int tid = threadIdx.x;

  // stage 0.5*||c||^2 for all centers (block-redundant, L2-served, cheap)
  #pragma unroll
  for (int r = 0; r < N_FCNS / K1_BLOCK; ++r) {
    int j = tid + r * K1_BLOCK;
    const float4* cp4 = (const float4*)(ctrs + j * D_IN);
    float a = 0.f;
    #pragma unroll
    for (int q = 0; q < D_IN / 4; ++q) {
      float4 v = cp4[q];
      a += v.x * v.x + v.y * v.y + v.z * v.z + v.w * v.w;
    }
    s_hcsq[j] = 0.5f * a;
  }
  __syncthreads();

  const int lane = tid & 63;
  // wave-uniform split id -> compiler can emit scalar loads for center rows
  const int split = __builtin_amdgcn_readfirstlane(tid >> 6);
  const int s = blockIdx.x * K1_SAMPLES + lane;

  float xr[D_IN];
  {
    const float4* xp = (const float4*)(x + (size_t)s * D_IN);
    #pragma unroll
    for (int q = 0; q < D_IN / 4; ++q) {
      float4 v = xp[q];
      xr[4 * q + 0] = v.x; xr[4 * q + 1] = v.y;
      xr[4 * q + 2] = v.z; xr[4 * q + 3] = v.w;
    }
  }

  // maximize u = x.c - 0.5||c||^2  (equivalent to minimizing d2)
  float u0 = -INFINITY, u1 = -INFINITY, u2 = -INFINITY, u3 = -INFINITY;
  int   i0 = -1, i1 = -1, i2 = -1, i3 = -1;

  const int jbase = split * K1_CPS;
  #pragma unroll 2
  for (int t = 0; t < K1_CPS; ++t) {
    const int j = jbase + t;
    const float* cp = ctrs + j * D_IN;   // wave-uniform address
    float acc = -s_hcsq[j];
    #pragma unroll
    for (int d = 0; d < D_IN; ++d) acc = fmaf(xr[d], cp[d], acc);
    if (acc > u3) {
      if (acc > u1) {
        if (acc > u0) { u3=u2;i3=i2; u2=u1;i2=i1; u1=u0;i1=i0; u0=acc;i0=j; }
        else          { u3=u2;i3=i2; u2=u1;i2=i1; u1=acc;i1=j; }
      } else {
        if (acc > u2) { u3=u2;i3=i2; u2=acc;i2=j; }
        else          { u3=acc;i3=j; }
      }
    }
  }
  s_u[split][lane][0] = u0; s_u[split][lane][1] = u1;
  s_u[split][lane][2] = u2; s_u[split][lane][3] = u3;
  s_i[split][lane][0] = i0; s_i[split][lane][1] = i1;
  s_i[split][lane][2] = i2; s_i[split][lane][3] = i3;
  __syncthreads();

  // one lane per sample: merge 32 candidates -> fp32 top-8 -> fp64 exact top-4
  if (tid < K1_SAMPLES) {
    float bu[8]; int bj[8];
    #pragma unroll
    for (int m = 0; m < 8; ++m) { bu[m] = -INFINITY; bj[m] = -1; }
    for (int w = 0; w < K1_SPLITS; ++w) {
      #pragma unroll
      for (int q = 0; q < 4; ++q) {
        float u = s_u[w][tid][q]; int j = s_i[w][tid][q];
        if (u > bu[7]) {
          bu[7] = u; bj[7] = j;
          #pragma unroll
          for (int m = 7; m > 0; --m) {
            if (bu[m] > bu[m - 1]) {
              float tu = bu[m]; bu[m] = bu[m - 1]; bu[m - 1] = tu;
              int   tj = bj[m]; bj[m] = bj[m - 1]; bj[m - 1] = tj;
            }
          }
        }
      }
    }
    // exact fp64 squared distances on the 8 survivors
    double bd[4]; int b4[4];
    #pragma unroll
    for (int m = 0; m < 4; ++m) { bd[m] = 1e300; b4[m] = 0x7fffffff; }
    for (int m = 0; m < 8; ++m) {
      int j = bj[m];
      const float* cp = ctrs + j * D_IN;
      double d2 = 0.0;
      #pragma unroll
      for (int d = 0; d < D_IN; ++d) {
        double df = (double)xr[d] - (double)cp[d];
        d2 = fma(df, df, d2);
      }
      bool ins = (d2 < bd[3]) || (d2 == bd[3] && j < b4[3]);
      if (ins) {
        bd[3] = d2; b4[3] = j;
        #pragma unroll
        for (int q = 3; q > 0; --q) {
          bool sw = (bd[q] < bd[q - 1]) || (bd[q] == bd[q - 1] && b4[q] < b4[q - 1]);
          if (sw) {
            double td = bd[q]; bd[q] = bd[q - 1]; bd[q - 1] = td;
            int    tj = b4[q]; b4[q] = b4[q - 1]; b4[q - 1] = tj;
          }
        }
      }
    }
    #pragma unroll
    for (int q = 0; q < 4; ++q) idx_out[s * KNN + q] = b4[q];
  }
}

// ---------------- Kernel 2: gather + apply local affine models ---------------
#define K2_BLOCK 256
#define K2_SAMPLES 32   // samples per block; thread = (sample, float4 col group)

__global__ __launch_bounds__(K2_BLOCK) void k_apply(
    const float* __restrict__ x, const float* __restrict__ ctrs,
    const float* __restrict__ wts, const float* __restrict__ offs,
    const int* __restrict__ idx, float* __restrict__ y)
{
  // +1 pad: per-(j,d) read across 8 samples would otherwise hit one bank
  __shared__ float s_diff[K2_SAMPLES][KNN][D_IN + 1];
  const int tid = threadIdx.x;
  const int sbase = blockIdx.x * K2_SAMPLES;

  // stage (x - c_j) per sample/neighbor
  for (int v = tid; v < K2_SAMPLES * KNN * D_IN; v += K2_BLOCK) {
    int d = v & 31; int p = v >> 5;         // p = sl*KNN + j
    int sl = p >> 2; int j = p & 3;
    int f = idx[(sbase + sl) * KNN + j];
    s_diff[sl][j][d] =
        x[(size_t)(sbase + sl) * D_IN + d] - ctrs[(size_t)f * D_IN + d];
  }
  __syncthreads();

  const int sl = tid >> 3;
  const int eq = tid & 7;
  const int s = sbase + sl;

  float4 acc = make_float4(0.f, 0.f, 0.f, 0.f);
  #pragma unroll
  for (int j = 0; j < KNN; ++j) {
    int f = idx[s * KNN + j];
    const float4* wp = (const float4*)(wts + (size_t)f * (D_IN * D_OUT));
    float4 ov = ((const float4*)(offs + (size_t)f * D_OUT))[eq];
    acc.x += ov.x; acc.y += ov.y; acc.z += ov.z; acc.w += ov.w;
    #pragma unroll
    for (int d = 0; d < D_IN; ++d) {
      float4 w = wp[d * (D_OUT / 4) + eq];
      float xc = s_diff[sl][j][d];
      acc.x = fmaf(xc, w.x, acc.x);
      acc.y = fmaf(xc, w.y, acc.y);
      acc.z = fmaf(xc, w.z, acc.z);
      acc.w = fmaf(xc, w.w, acc.w);
    }
  }
  ((float4*)(y + (size_t)s * D_OUT))[eq] = acc;
}

// ---------------- launch -----------------------------------------------------
extern "C" void kernel_launch(void* const* d_in, const int* in_sizes, int n_in,
                              void* d_out, int out_size, void* d_ws, size_t ws_size,
                              hipStream_t stream) {
  const float* x    = (const float*)d_in[0];
  const float* ctrs = (const float*)d_in[1];
  const float* wts  = (const float*)d_in[2];
  const float* offs = (const float*)d_in[3];
  int*   idxb = (int*)d_ws;           // 16384*4 ints = 256 KB scratch
  float* y    = (float*)d_out;

  k_topk<<<N_SMPS / K1_SAMPLES, K1_BLOCK, 0, stream>>>(x, ctrs, idxb);
  k_apply<<<N_SMPS / K2_SAMPLES, K2_BLOCK, 0, stream>>>(x, ctrs, wts, offs,
                                                        idxb, y);
}

// Round 2
// 164.273 us; speedup vs baseline: 1.0663x; 1.0663x over previous
//
#include <hip/hip_runtime.h>
#include <math.h>

#define N_SMPS 16384
#define N_FCNS 2048
#define D_IN 32
#define D_OUT 32
#define KNN 4

// ---------------- Kernel 1: distance + top-k (with fp64 refinement) ----------
// Block = 1024 threads = 16 waves. Each wave: 64 samples (one per lane) vs a
// 128-center split. 256 blocks -> 1 block/CU, 16 waves/CU (50% occupancy).
#define K1_BLOCK 1024
#define K1_SPLITS 16
#define K1_CPS (N_FCNS / K1_SPLITS)    // 128 centers per split
#define K1_SAMPLES 64

__global__ __launch_bounds__(K1_BLOCK, 4) void k_topk(
    const float* __restrict__ x, const float* __restrict__ ctrs,
    int* __restrict__ idx_out)
{
  __shared__ float s_hcsq[N_FCNS];
  __shared__ float s_u[K1_SPLITS][K1_SAMPLES][5];   // [5]: bank-stagger pad
  __shared__ int   s_i[K1_SPLITS][K1_SAMPLES][5];

  const int tid = threadIdx.x;

  // stage 0.5*||c||^2 for all centers (block-redundant, L2-served, cheap)
  #pragma unroll
  for (int r = 0; r < N_FCNS / K1_BLOCK; ++r) {
    int j = tid + r * K1_BLOCK;
    const float4* cp4 = (const float4*)(ctrs + j * D_IN);
    float a = 0.f;
    #pragma unroll
    for (int q = 0; q < D_IN / 4; ++q) {
      float4 v = cp4[q];
      a += v.x * v.x + v.y * v.y + v.z * v.z + v.w * v.w;
    }
    s_hcsq[j] = 0.5f * a;
  }
  __syncthreads();

  const int lane = tid & 63;
  // wave-uniform split id -> compiler emits scalar loads for center rows
  const int split = __builtin_amdgcn_readfirstlane(tid >> 6);
  const int s = blockIdx.x * K1_SAMPLES + lane;

  float xr[D_IN];
  {
    const float4* xp = (const float4*)(x + (size_t)s * D_IN);
    #pragma unroll
    for (int q = 0; q < D_IN / 4; ++q) {
      float4 v = xp[q];
      xr[4 * q + 0] = v.x; xr[4 * q + 1] = v.y;
      xr[4 * q + 2] = v.z; xr[4 * q + 3] = v.w;
    }
  }

  // maximize u = x.c - 0.5||c||^2  (equivalent to minimizing d2)
  float u0 = -INFINITY, u1 = -INFINITY, u2 = -INFINITY, u3 = -INFINITY;
  int   i0 = -1, i1 = -1, i2 = -1, i3 = -1;

  const int jbase = split * K1_CPS;
  #pragma unroll 2
  for (int t = 0; t < K1_CPS; ++t) {
    const int j = jbase + t;
    const float* cp = ctrs + j * D_IN;   // wave-uniform address -> s_load
    // 4 independent partial accumulators: dep-chain 8*4cyc < issue 64cyc
    float a0 = -s_hcsq[j], a1 = 0.f, a2 = 0.f, a3 = 0.f;
    #pragma unroll
    for (int d = 0; d < D_IN; d += 4) {
      a0 = fmaf(xr[d + 0], cp[d + 0], a0);
      a1 = fmaf(xr[d + 1], cp[d + 1], a1);
      a2 = fmaf(xr[d + 2], cp[d + 2], a2);
      a3 = fmaf(xr[d + 3], cp[d + 3], a3);
    }
    const float acc = (a0 + a1) + (a2 + a3);
    if (acc > u3) {
      if (acc > u1) {
        if (acc > u0) { u3=u2;i3=i2; u2=u1;i2=i1; u1=u0;i1=i0; u0=acc;i0=j; }
        else          { u3=u2;i3=i2; u2=u1;i2=i1; u1=acc;i1=j; }
      } else {
        if (acc > u2) { u3=u2;i3=i2; u2=acc;i2=j; }
        else          { u3=acc;i3=j; }
      }
    }
  }
  s_u[split][lane][0] = u0; s_u[split][lane][1] = u1;
  s_u[split][lane][2] = u2; s_u[split][lane][3] = u3;
  s_i[split][lane][0] = i0; s_i[split][lane][1] = i1;
  s_i[split][lane][2] = i2; s_i[split][lane][3] = i3;
  __syncthreads();

  // one lane per sample: merge 64 candidates -> fp32 top-8 -> fp64 exact top-4
  if (tid < K1_SAMPLES) {
    float bu[8]; int bj[8];
    #pragma unroll
    for (int m = 0; m < 8; ++m) { bu[m] = -INFINITY; bj[m] = -1; }
    for (int w = 0; w < K1_SPLITS; ++w) {
      #pragma unroll
      for (int q = 0; q < 4; ++q) {
        float u = s_u[w][tid][q]; int j = s_i[w][tid][q];
        if (u > bu[7]) {
          bu[7] = u; bj[7] = j;
          #pragma unroll
          for (int m = 7; m > 0; --m) {
            if (bu[m] > bu[m - 1]) {
              float tu = bu[m]; bu[m] = bu[m - 1]; bu[m - 1] = tu;
              int   tj = bj[m]; bj[m] = bj[m - 1]; bj[m - 1] = tj;
            }
          }
        }
      }
    }
    // exact fp64 squared distances on the 8 survivors
    double bd[4]; int b4[4];
    #pragma unroll
    for (int m = 0; m < 4; ++m) { bd[m] = 1e300; b4[m] = 0x7fffffff; }
    for (int m = 0; m < 8; ++m) {
      int j = bj[m];
      const float* cp = ctrs + j * D_IN;
      double d2 = 0.0;
      #pragma unroll
      for (int d = 0; d < D_IN; ++d) {
        double df = (double)xr[d] - (double)cp[d];
        d2 = fma(df, df, d2);
      }
      bool ins = (d2 < bd[3]) || (d2 == bd[3] && j < b4[3]);
      if (ins) {
        bd[3] = d2; b4[3] = j;
        #pragma unroll
        for (int q = 3; q > 0; --q) {
          bool sw = (bd[q] < bd[q - 1]) || (bd[q] == bd[q - 1] && b4[q] < b4[q - 1]);
          if (sw) {
            double td = bd[q]; bd[q] = bd[q - 1]; bd[q - 1] = td;
            int    tj = b4[q]; b4[q] = b4[q - 1]; b4[q - 1] = tj;
          }
        }
      }
    }
    #pragma unroll
    for (int q = 0; q < 4; ++q) idx_out[s * KNN + q] = b4[q];
  }
}

// ---------------- Kernel 2: gather + apply local affine models ---------------
#define K2_BLOCK 256
#define K2_SAMPLES 32   // samples per block; thread = (sample, float4 col group)

__global__ __launch_bounds__(K2_BLOCK) void k_apply(
    const float* __restrict__ x, const float* __restrict__ ctrs,
    const float* __restrict__ wts, const float* __restrict__ offs,
    const int* __restrict__ idx, float* __restrict__ y)
{
  // +1 pad: per-(j,d) read across 8 samples would otherwise hit one bank
  __shared__ float s_diff[K2_SAMPLES][KNN][D_IN + 1];
  const int tid = threadIdx.x;
  const int sbase = blockIdx.x * K2_SAMPLES;

  // stage (x - c_j) per sample/neighbor
  for (int v = tid; v < K2_SAMPLES * KNN * D_IN; v += K2_BLOCK) {
    int d = v & 31; int p = v >> 5;         // p = sl*KNN + j
    int sl = p >> 2; int j = p & 3;
    int f = idx[(sbase + sl) * KNN + j];
    s_diff[sl][j][d] =
        x[(size_t)(sbase + sl) * D_IN + d] - ctrs[(size_t)f * D_IN + d];
  }
  __syncthreads();

  const int sl = tid >> 3;
  const int eq = tid & 7;
  const int s = sbase + sl;

  float4 acc = make_float4(0.f, 0.f, 0.f, 0.f);
  #pragma unroll
  for (int j = 0; j < KNN; ++j) {
    int f = idx[s * KNN + j];
    const float4* wp = (const float4*)(wts + (size_t)f * (D_IN * D_OUT));
    float4 ov = ((const float4*)(offs + (size_t)f * D_OUT))[eq];
    acc.x += ov.x; acc.y += ov.y; acc.z += ov.z; acc.w += ov.w;
    #pragma unroll
    for (int d = 0; d < D_IN; ++d) {
      float4 w = wp[d * (D_OUT / 4) + eq];
      float xc = s_diff[sl][j][d];
      acc.x = fmaf(xc, w.x, acc.x);
      acc.y = fmaf(xc, w.y, acc.y);
      acc.z = fmaf(xc, w.z, acc.z);
      acc.w = fmaf(xc, w.w, acc.w);
    }
  }
  ((float4*)(y + (size_t)s * D_OUT))[eq] = acc;
}

// ---------------- launch -----------------------------------------------------
extern "C" void kernel_launch(void* const* d_in, const int* in_sizes, int n_in,
                              void* d_out, int out_size, void* d_ws, size_t ws_size,
                              hipStream_t stream) {
  const float* x    = (const float*)d_in[0];
  const float* ctrs = (const float*)d_in[1];
  const float* wts  = (const float*)d_in[2];
  const float* offs = (const float*)d_in[3];
  int*   idxb = (int*)d_ws;           // 16384*4 ints = 256 KB scratch
  float* y    = (float*)d_out;

  k_topk<<<N_SMPS / K1_SAMPLES, K1_BLOCK, 0, stream>>>(x, ctrs, idxb);
  k_apply<<<N_SMPS / K2_SAMPLES, K2_BLOCK, 0, stream>>>(x, ctrs, wts, offs,
                                                        idxb, y);
}